// Round 4
// baseline (240.151 us; speedup 1.0000x reference)
//
#include <hip/hip_runtime.h>
#include <hip/hip_bf16.h>
#include <math.h>

typedef __bf16 bf16;
typedef __bf16 bf16x4 __attribute__((ext_vector_type(4)));
typedef __bf16 bf16x8 __attribute__((ext_vector_type(8)));
typedef float f32x4 __attribute__((ext_vector_type(4)));

#define BB  128
#define TT  64
#define BTT 8192
#define HH  512
#define EE  1024
#define KA  49
#define NV  10000

__device__ __forceinline__ float ftanh(float x) {
    float cx = fminf(fmaxf(x, -15.f), 15.f);
    float e = __expf(2.f * cx);
    return (e - 1.f) * __builtin_amdgcn_rcpf(e + 1.f);
}
__device__ __forceinline__ float fsigmoid(float x) {
    return __builtin_amdgcn_rcpf(1.f + __expf(-x));
}

// ---------------- fused converts (one pass, float4 -> bf16x4) ----------------
__device__ __forceinline__ void cvt4(const float* __restrict__ s, bf16* __restrict__ d) {
    f32x4 v = *(const f32x4*)s;
    bf16x4 o = { (bf16)v[0], (bf16)v[1], (bf16)v[2], (bf16)v[3] };
    *(bf16x4*)d = o;
}
// nt variant: single-use f32 source, evict-first so bf16 working set stays in L2
__device__ __forceinline__ void cvt4nt(const float* __restrict__ s, bf16* __restrict__ d) {
    f32x4 v = __builtin_nontemporal_load((const f32x4*)s);
    bf16x4 o = { (bf16)v[0], (bf16)v[1], (bf16)v[2], (bf16)v[3] };
    *(bf16x4*)d = o;
}

// Wm handled by filler blocks in gate_mid128; hpb eliminated (shifted-hb staging + zero page).
__global__ __launch_bounds__(256)
void prep_kernel(const float* __restrict__ x, const float* __restrict__ hid,
                 const float* __restrict__ V, const float* __restrict__ Wv,
                 const float* __restrict__ Wg, const float* __restrict__ Ws,
                 const float* __restrict__ Wx, const float* __restrict__ Wsh,
                 bf16* __restrict__ xb, bf16* __restrict__ hb,
                 bf16* __restrict__ Vb, bf16* __restrict__ Wvb, bf16* __restrict__ Wgb,
                 bf16* __restrict__ Wsb, bf16* __restrict__ Wxb, bf16* __restrict__ Wshb,
                 bf16* __restrict__ zbuf)
{
    if (blockIdx.x == 0 && threadIdx.x < 128) {   // 1024-elem zero page for hprev t==0 rows
        bf16x8 z = {};
        *(bf16x8*)(zbuf + threadIdx.x * 8) = z;
    }

    const long NX = (long)BTT * EE;
    const long NH = (long)BTT * HH;
    const long NVV = (long)BB * KA * HH;
    const long NWX = (long)HH * EE;
    const long NWSH = (long)HH * HH;
    const long NW = (long)KA * HH;
    const long total4 = (NX + NH + NVV + NWX + NWSH + 3 * NW) >> 2;

    long t0 = (long)blockIdx.x * 256 + threadIdx.x;
    long st = (long)gridDim.x * 256;
    for (long i4 = t0; i4 < total4; i4 += st) {
        long i = i4 << 2;
        if (i < NX) { cvt4nt(x + i, xb + i); continue; }
        i -= NX;
        if (i < NH) { cvt4(hid + i, hb + i); continue; }
        i -= NH;
        if (i < NVV) { cvt4nt(V + i, Vb + i); continue; }
        i -= NVV;
        if (i < NWX) { cvt4nt(Wx + i, Wxb + i); continue; }
        i -= NWX;
        if (i < NWSH) { cvt4nt(Wsh + i, Wshb + i); continue; }
        i -= NWSH;
        if (i < NW) { cvt4nt(Wv + i, Wvb + i); continue; }
        i -= NW;
        if (i < NW) { cvt4nt(Wg + i, Wgb + i); continue; }
        i -= NW;
        cvt4nt(Ws + i, Wsb + i);
    }
}

// ---------------- pipelined 128x128 GEMM core (ring-4 BK=32, lookahead-3, counted vmcnt) ----
// C = A1@B1^T (+ A2@B2^T), row-major bf16, K-contiguous. 4 waves (2x2), wave = 64x64.
// SHIFT: A2 rows read shifted down by one (row r reads A2 row r-1; rows r%64==0 read zbuf).
// EPI 0: sentb[r,c] = bf16(sigmoid(acc)*tanh(eaux[r*ldo+c]))
// EPI 2: ((float*)out)[r*ldo+c] = acc   (masked c < N)
template<int EPI, bool SHIFT>
__device__ __forceinline__ void gemm128_core(
    bf16* smem,
    const bf16* __restrict__ A1, const bf16* __restrict__ B1, int K1,
    const bf16* __restrict__ A2, const bf16* __restrict__ B2, int K2,
    int N, const float* __restrict__ eaux, void* __restrict__ outv, int ldo,
    int bm0, int bn0, const bf16* __restrict__ zbuf)
{
    const int tid = threadIdx.x;
    const int lane = tid & 63;
    const int wid = tid >> 6;
    const int wm = (wid >> 1) * 64;
    const int wn = (wid & 1) * 64;
    const int rA = lane & 15;
    const int ks = lane >> 4;
    const int swzB = (ks ^ ((rA >> 1) & 3)) * 16;   // frag-read byte slot (row-swizzle)

    // staging: 512 16B-chunks per 8KB matrix tile; thread covers chunks c0, c1
    const int c0 = tid, c1 = tid + 256;
    const int row0 = c0 >> 2, row1 = c1 >> 2;
    const int gc0 = ((c0 & 3) ^ ((row0 >> 1) & 3)) * 8;  // pre-swizzled global col (elems)
    const int gc1 = ((c1 & 3) ^ ((row1 >> 1) & 3)) * 8;
    const int br0 = (bn0 + row0 < N) ? bn0 + row0 : N - 1;
    const int br1 = (bn0 + row1 < N) ? bn0 + row1 : N - 1;

    const int NT1 = K1 >> 5;
    const int NT2 = K2 >> 5;
    const int NT = NT1 + NT2;

    // hoisted per-row source pointers
    const bf16* A1r0 = A1 + (size_t)(bm0 + row0) * K1 + gc0;
    const bf16* A1r1 = A1 + (size_t)(bm0 + row1) * K1 + gc1;
    const bf16* B1r0 = B1 + (size_t)br0 * K1 + gc0;
    const bf16* B1r1 = B1 + (size_t)br1 * K1 + gc1;
    const bf16 *A2r0 = nullptr, *A2r1 = nullptr, *B2r0 = nullptr, *B2r1 = nullptr;
    if (K2 > 0) {
        if (SHIFT) {
            A2r0 = (((bm0 + row0) & 63) == 0) ? zbuf + gc0
                                              : A2 + (size_t)(bm0 + row0 - 1) * K2 + gc0;
            A2r1 = (((bm0 + row1) & 63) == 0) ? zbuf + gc1
                                              : A2 + (size_t)(bm0 + row1 - 1) * K2 + gc1;
        } else {
            A2r0 = A2 + (size_t)(bm0 + row0) * K2 + gc0;
            A2r1 = A2 + (size_t)(bm0 + row1) * K2 + gc1;
        }
        B2r0 = B2 + (size_t)br0 * K2 + gc0;
        B2r1 = B2 + (size_t)br1 * K2 + gc1;
    }

    auto stage = [&](int t) {
        const bf16 *a0, *a1, *b0, *b1; int k0;
        if (t < NT1) { k0 = t << 5;          a0 = A1r0; a1 = A1r1; b0 = B1r0; b1 = B1r1; }
        else         { k0 = (t - NT1) << 5;  a0 = A2r0; a1 = A2r1; b0 = B2r0; b1 = B2r1; }
        char* base = (char*)smem + (t & 3) * 16384;
        __builtin_amdgcn_global_load_lds(
            (const __attribute__((address_space(1))) unsigned int*)(a0 + k0),
            (__attribute__((address_space(3))) unsigned int*)(base + c0 * 16), 16, 0, 0);
        __builtin_amdgcn_global_load_lds(
            (const __attribute__((address_space(1))) unsigned int*)(a1 + k0),
            (__attribute__((address_space(3))) unsigned int*)(base + c1 * 16), 16, 0, 0);
        __builtin_amdgcn_global_load_lds(
            (const __attribute__((address_space(1))) unsigned int*)(b0 + k0),
            (__attribute__((address_space(3))) unsigned int*)(base + 8192 + c0 * 16), 16, 0, 0);
        __builtin_amdgcn_global_load_lds(
            (const __attribute__((address_space(1))) unsigned int*)(b1 + k0),
            (__attribute__((address_space(3))) unsigned int*)(base + 8192 + c1 * 16), 16, 0, 0);
    };

    f32x4 acc[4][4] = {};

    // prologue: tiles 0,1,2 (12 loads/thread); vmcnt(8) -> tile 0 landed
    stage(0); stage(1); stage(2);
    asm volatile("s_waitcnt vmcnt(8)" ::: "memory");
    __builtin_amdgcn_s_barrier();

    for (int t = 0; t < NT; ++t) {
        const char* sA = (const char*)smem + (t & 3) * 16384;
        const char* sB = sA + 8192;

        bf16x8 af[4], bfr[4];
        #pragma unroll
        for (int mi = 0; mi < 4; ++mi)
            af[mi] = *(const bf16x8*)(sA + (wm + mi * 16 + rA) * 64 + swzB);
        #pragma unroll
        for (int ni = 0; ni < 4; ++ni)
            bfr[ni] = *(const bf16x8*)(sB + (wn + ni * 16 + rA) * 64 + swzB);

        if (t + 3 < NT) {
            stage(t + 3);                                    // 12 outstanding
            asm volatile("s_waitcnt vmcnt(8)" ::: "memory"); // tile t+1 landed
        } else if (t + 2 < NT) {
            asm volatile("s_waitcnt vmcnt(4)" ::: "memory"); // tile t+1 landed
        } else {
            asm volatile("s_waitcnt vmcnt(0)" ::: "memory");
        }
        __builtin_amdgcn_s_barrier();

        __builtin_amdgcn_s_setprio(1);
        #pragma unroll
        for (int mi = 0; mi < 4; ++mi) {
            #pragma unroll
            for (int ni = 0; ni < 4; ++ni)
                acc[mi][ni] = __builtin_amdgcn_mfma_f32_16x16x32_bf16(af[mi], bfr[ni], acc[mi][ni], 0, 0, 0);
        }
        __builtin_amdgcn_s_setprio(0);
        __builtin_amdgcn_s_barrier();
    }

    // C/D layout: col = lane&15, row = (lane>>4)*4 + reg
    #pragma unroll
    for (int mi = 0; mi < 4; ++mi) {
        #pragma unroll
        for (int ni = 0; ni < 4; ++ni) {
            const int col = bn0 + wn + ni * 16 + rA;
            if (col < N) {
                #pragma unroll
                for (int r = 0; r < 4; ++r) {
                    const int rowg = bm0 + wm + mi * 16 + ks * 4 + r;
                    float v = acc[mi][ni][r];
                    if (EPI == 0) {
                        ((bf16*)outv)[(size_t)rowg * ldo + col] =
                            (bf16)(fsigmoid(v) * ftanh(eaux[(size_t)rowg * ldo + col]));
                    } else {
                        ((float*)outv)[(size_t)rowg * ldo + col] = v;
                    }
                }
            }
        }
    }
}

// merged launch: gate (256) + cv (49) + cg (64) + Wm-convert filler (143) = 512 blocks
__global__ __launch_bounds__(256, 2)
void gate_mid128(const bf16* __restrict__ xb, const bf16* __restrict__ Wxb,
                 const bf16* __restrict__ Wshb,
                 const float* __restrict__ cel, bf16* __restrict__ sentb,
                 const bf16* __restrict__ Vb, const bf16* __restrict__ Wvb,
                 const bf16* __restrict__ hb, const bf16* __restrict__ Wgb,
                 float* __restrict__ cv, float* __restrict__ cg,
                 const float* __restrict__ Wm, bf16* __restrict__ Wmb,
                 const bf16* __restrict__ zbuf)
{
    __shared__ bf16 smem[4 * 8192];
    const int bid = blockIdx.x;
    if (bid >= 369) {
        const long n4 = ((long)NV * HH) >> 2;
        for (long i4 = (long)(bid - 369) * 256 + threadIdx.x; i4 < n4; i4 += 143L * 256)
            cvt4nt(Wm + (i4 << 2), Wmb + (i4 << 2));
        return;
    }
    if (bid < 256) {
        const int bm0 = (bid >> 2) * 128;
        const int bn0 = (bid & 3) * 128;
        // gate = x@Wx^T + hprev@Wsh^T, hprev = hb shifted one row (zero at t==0)
        gemm128_core<0, true>(smem, xb, Wxb, EE, hb, Wshb, HH, HH, cel, (void*)sentb, HH,
                              bm0, bn0, zbuf);
    } else if (bid < 305) {
        gemm128_core<2, false>(smem, Vb, Wvb, HH, nullptr, nullptr, 0, KA, nullptr,
                               (void*)cv, KA, (bid - 256) * 128, 0, nullptr);
    } else {
        gemm128_core<2, false>(smem, hb, Wgb, HH, nullptr, nullptr, 0, KA, nullptr,
                               (void*)cg, KA, (bid - 305) * 128, 0, nullptr);
    }
}

// ---------------- fused middle: cs (MFMA) + z/softmax + cch, one block per 32 bt rows ------
// Grid 256 = 128 batches x 2 halves. 4 waves. LDS ~126 KB -> 1 block/CU (256 blocks = full).
// Phase 1: cs32 = sent[r0..r0+31] @ Ws^T via MFMA (K=512, N pad 49->64, row-clamped).
// Phase 2: z[t,k] = sum_n tanh(cv[k,n]+cg[t,n])wh[n]; z_ext from csL+cg; softmax -> alpha,beta.
// Phase 3: c = alpha@V (V in LDS), ch = beta*sent + (1-beta)*c + hid -> chb.
__global__ __launch_bounds__(256, 1)
void fused_mid(const float* __restrict__ cv, const float* __restrict__ cg,
               const float* __restrict__ wh, const bf16* __restrict__ sentb,
               const bf16* __restrict__ Wsb, const bf16* __restrict__ Vb,
               const float* __restrict__ hid, float* __restrict__ alpha,
               float* __restrict__ beta, bf16* __restrict__ chb)
{
    __shared__ char Lm[128968];
    bf16* sentL = (bf16*)Lm;                    // 16 tiles x [32 rows][64B], swizzled (32 KB)
    char* WsL   = Lm + 32768;                   // 16 tiles x [64 rows][64B], swizzled (64 KB)
    bf16* VL    = (bf16*)(Lm + 32768);          // later: V [49][512] linear (50 KB, reuse)
    float* csL  = (float*)(Lm + 98304);         // [32][64]
    float* cvL  = (float*)(Lm + 106496);        // [49*49]
    float* cgL  = (float*)(Lm + 116100);        // [32*49]
    float* alphaL = (float*)(Lm + 122372);      // [32*49]
    float* whL  = (float*)(Lm + 128644);        // [49]
    float* bL   = (float*)(Lm + 128840);        // [32]

    const int bid = blockIdx.x;
    const int b = bid >> 1;
    const int r0 = b * 64 + (bid & 1) * 32;
    const int tid = threadIdx.x;
    const int lane = tid & 63;
    const int wid = tid >> 6;

    // ---- stage sentL: 2048 chunks (8/thread), pre-swizzled source, linear dest ----
    #pragma unroll
    for (int i = 0; i < 8; ++i) {
        const int cgk = tid + i * 256;
        const int kt = cgk >> 7, c = cgk & 127;
        const int row = c >> 2, slot = c & 3;
        const int gcol = kt * 32 + ((slot ^ ((row >> 1) & 3)) * 8);
        __builtin_amdgcn_global_load_lds(
            (const __attribute__((address_space(1))) unsigned int*)(sentb + (size_t)(r0 + row) * HH + gcol),
            (__attribute__((address_space(3))) unsigned int*)((char*)sentL + kt * 2048 + c * 16), 16, 0, 0);
    }
    // ---- stage WsL: 4096 chunks (16/thread), rows >= 49 clamped (cols masked later) ----
    #pragma unroll
    for (int i = 0; i < 16; ++i) {
        const int cgk = tid + i * 256;
        const int kt = cgk >> 8, c = cgk & 255;
        const int row = c >> 2, slot = c & 3;
        const int rowc = (row < KA) ? row : KA - 1;
        const int gcol = kt * 32 + ((slot ^ ((row >> 1) & 3)) * 8);
        __builtin_amdgcn_global_load_lds(
            (const __attribute__((address_space(1))) unsigned int*)(Wsb + (size_t)rowc * HH + gcol),
            (__attribute__((address_space(3))) unsigned int*)(WsL + kt * 4096 + c * 16), 16, 0, 0);
    }
    asm volatile("s_waitcnt vmcnt(0)" ::: "memory");
    __builtin_amdgcn_s_barrier();

    // ---- phase 1: MFMA. wave (wm = wid>>1, wn = wid&1): rows 16wm..+15, cols 32wn..+31 ----
    const int wm = wid >> 1, wn = wid & 1;
    const int rA = lane & 15, ks = lane >> 4;
    const int swz = (ks ^ ((rA >> 1) & 3)) * 16;
    f32x4 acc2[2] = {};
    #pragma unroll
    for (int kt = 0; kt < 16; ++kt) {
        bf16x8 af = *(const bf16x8*)((char*)sentL + kt * 2048 + (wm * 16 + rA) * 64 + swz);
        #pragma unroll
        for (int ni = 0; ni < 2; ++ni) {
            bf16x8 bf_ = *(const bf16x8*)(WsL + kt * 4096 + (wn * 32 + ni * 16 + rA) * 64 + swz);
            acc2[ni] = __builtin_amdgcn_mfma_f32_16x16x32_bf16(af, bf_, acc2[ni], 0, 0, 0);
        }
    }
    // dump cs to LDS: col = lane&15 (+16ni+32wn), row = ks*4+r (+16wm)
    #pragma unroll
    for (int ni = 0; ni < 2; ++ni) {
        #pragma unroll
        for (int r = 0; r < 4; ++r) {
            const int row = wm * 16 + ks * 4 + r;
            const int col = wn * 32 + ni * 16 + rA;
            csL[row * 64 + col] = acc2[ni][r];
        }
    }
    __syncthreads();   // csL ready; sentL reads done; WsL dead -> VL staging safe

    // ---- stage VL (linear, 3136 chunks) + cv/cg/wh scalar loads ----
    for (int i = 0; i < 13; ++i) {
        const int c = tid + i * 256;
        if (c < (KA * HH * 2) / 16) {
            __builtin_amdgcn_global_load_lds(
                (const __attribute__((address_space(1))) unsigned int*)(Vb + (size_t)b * KA * HH + c * 8),
                (__attribute__((address_space(3))) unsigned int*)((char*)VL + c * 16), 16, 0, 0);
        }
    }
    for (int i = tid; i < KA * KA; i += 256) cvL[i] = cv[(size_t)b * KA * KA + i];
    for (int i = tid; i < 32 * KA; i += 256) cgL[i] = cg[(size_t)r0 * KA + i];
    if (tid < KA) whL[tid] = wh[tid];
    __syncthreads();   // drains VL loads too (accepted cost); cvL/cgL/whL visible

    // ---- phase 2: z + softmax (4 waves x 8 rows, mirrors softz_kernel) ----
    for (int j = 0; j < 8; ++j) {
        const int t = wid * 8 + j;
        float z = -INFINITY;
        if (lane < KA) {
            const float* cvk = cvL + lane * KA;
            const float* cgr = cgL + t * KA;
            float a = 0.f;
            #pragma unroll 7
            for (int n = 0; n < KA; ++n)
                a += ftanh(cvk[n] + cgr[n]) * whL[n];
            z = a;
        }
        const float csv = (lane < KA) ? csL[t * 64 + lane] + cgL[t * KA + lane] : 0.f;
        float u = (lane < KA) ? ftanh(csv) * whL[lane] : 0.f;

        float m1 = z;
        #pragma unroll
        for (int o = 32; o; o >>= 1) m1 = fmaxf(m1, __shfl_xor(m1, o, 64));
        float e = (lane < KA) ? __expf(z - m1) : 0.f;
        float s1 = e, ze = u;
        #pragma unroll
        for (int o = 32; o; o >>= 1) { s1 += __shfl_xor(s1, o, 64); ze += __shfl_xor(ze, o, 64); }

        if (lane < KA) {
            const float av = e / s1;
            alpha[(size_t)(r0 + t) * KA + lane] = av;
            alphaL[t * KA + lane] = av;
        }
        if (lane == 0) {
            const float M2 = fmaxf(m1, ze);
            const float denom = s1 * __expf(m1 - M2) + __expf(ze - M2);
            const float bv = __expf(ze - M2) / denom;
            beta[r0 + t] = bv;
            bL[t] = bv;
        }
    }
    __syncthreads();   // alphaL/bL ready; VL landed (drained above)

    // ---- phase 3: cch. thread owns h = hc*256+tid; sent re-read from swizzled sentL ----
    #pragma unroll
    for (int hc = 0; hc < 2; ++hc) {
        const int h = hc * 256 + tid;
        float vreg[KA];
        #pragma unroll
        for (int k = 0; k < KA; ++k) vreg[k] = (float)VL[k * HH + h];
        const int kt = h >> 5, gslot = (h >> 3) & 3, off = h & 7;
        #pragma unroll 4
        for (int t = 0; t < 32; ++t) {
            const float* ar = alphaL + t * KA;
            float c = 0.f;
            #pragma unroll
            for (int k = 0; k < KA; ++k) c += ar[k] * vreg[k];
            const float be = bL[t];
            const size_t idx = (size_t)(r0 + t) * HH + h;
            // sent from sentL (swizzled): slot = gslot ^ ((t>>1)&3)
            const bf16 sv = *(const bf16*)((char*)sentL + kt * 2048 + t * 64 +
                                           ((gslot ^ ((t >> 1) & 3)) * 16) + off * 2);
            const float ch = be * (float)sv + (1.f - be) * c
                           + __builtin_nontemporal_load(hid + idx);
            chb[idx] = (bf16)ch;
        }
    }
}

// ---------------- 256x128 deep-pipelined GEMM for the output projection ----------------
// M=8192, N=10000 (grid 32x79), K=512. BK=32, ring-3 LDS (72 KiB -> 2 blocks/CU),
// 8 waves (4Mx2N), lookahead-2 (vmcnt(3) steady state), raw s_barrier, setprio.
// Epilogue: per-wave LDS transpose -> fully-coalesced nontemporal dwordx4 stores.
__global__ __launch_bounds__(512, 4)
void gemm256x128_bias(const bf16* __restrict__ A, const bf16* __restrict__ B,
                      const float* __restrict__ bias, float* __restrict__ out)
{
    const int K = HH;        // 512
    const int N = NV;        // 10000
    const int NT = K / 32;   // 16
    const int ntn = 79;      // ceil(10000/128)

    __shared__ bf16 smem[3 * 12288];   // ring slot: [A 16KB][B 8KB] = 24 KB

    // XCD-bijective swizzle (nwg = 2528, 2528/8 = 316)
    const int bid = blockIdx.x;
    const int wg = (bid & 7) * 316 + (bid >> 3);
    const int bm0 = (wg / ntn) * 256;
    const int bn0 = (wg % ntn) * 128;

    const int tid = threadIdx.x;
    const int lane = tid & 63;
    const int wid = tid >> 6;
    const int wr = (wid >> 1) * 64;   // 4 M-waves
    const int wc = (wid & 1) * 64;    // 2 N-waves
    const int rA = lane & 15;
    const int ks = lane >> 4;
    const int swz = (ks ^ ((rA >> 1) & 3)) * 16;

    // staging: A 1024 chunks (2/thread), B 512 chunks (1/thread)
    const int arow0 = tid >> 2;             // 0..127
    const int arow1 = arow0 + 128;          // 128..255
    const int gcA0 = ((tid & 3) ^ ((arow0 >> 1) & 3)) * 8;
    const int gcA1 = ((tid & 3) ^ ((arow1 >> 1) & 3)) * 8;
    const int brow = tid >> 2;              // 0..127
    const int gcB  = ((tid & 3) ^ ((brow >> 1) & 3)) * 8;
    const int browc = (bn0 + brow < N) ? bn0 + brow : N - 1;

    const bf16* Ap0 = A + (size_t)(bm0 + arow0) * K + gcA0;
    const bf16* Ap1 = A + (size_t)(bm0 + arow1) * K + gcA1;
    const bf16* Bp  = B + (size_t)browc * K + gcB;

    auto stage = [&](int t, int slot) {
        char* base = (char*)smem + slot * 24576;
        const int k0 = t << 5;
        __builtin_amdgcn_global_load_lds(
            (const __attribute__((address_space(1))) unsigned int*)(Ap0 + k0),
            (__attribute__((address_space(3))) unsigned int*)(base + tid * 16), 16, 0, 0);
        __builtin_amdgcn_global_load_lds(
            (const __attribute__((address_space(1))) unsigned int*)(Ap1 + k0),
            (__attribute__((address_space(3))) unsigned int*)(base + (tid + 512) * 16), 16, 0, 0);
        __builtin_amdgcn_global_load_lds(
            (const __attribute__((address_space(1))) unsigned int*)(Bp + k0),
            (__attribute__((address_space(3))) unsigned int*)(base + 16384 + tid * 16), 16, 0, 0);
    };

    f32x4 acc[4][4] = {};

    // prologue: tiles 0,1 into slots 0,1 (6 loads/thread); vmcnt(3) -> tile 0 landed
    stage(0, 0); stage(1, 1);
    asm volatile("s_waitcnt vmcnt(3)" ::: "memory");
    __builtin_amdgcn_s_barrier();

    int slR = 0, slS = 2;
    for (int t = 0; t < NT; ++t) {
        const char* sA = (const char*)smem + slR * 24576;
        const char* sB = sA + 16384;

        bf16x8 af[4], bfr[4];
        #pragma unroll
        for (int mi = 0; mi < 4; ++mi)
            af[mi] = *(const bf16x8*)(sA + (wr + mi * 16 + rA) * 64 + swz);
        #pragma unroll
        for (int ni = 0; ni < 4; ++ni)
            bfr[ni] = *(const bf16x8*)(sB + (wc + ni * 16 + rA) * 64 + swz);

        if (t + 2 < NT) {
            stage(t + 2, slS);                               // 6 outstanding
            asm volatile("s_waitcnt vmcnt(3)" ::: "memory"); // tile t+1 landed
        } else {
            asm volatile("s_waitcnt vmcnt(0)" ::: "memory");
        }
        __builtin_amdgcn_s_barrier();

        __builtin_amdgcn_s_setprio(1);
        #pragma unroll
        for (int mi = 0; mi < 4; ++mi) {
            #pragma unroll
            for (int ni = 0; ni < 4; ++ni)
                acc[mi][ni] = __builtin_amdgcn_mfma_f32_16x16x32_bf16(af[mi], bfr[ni], acc[mi][ni], 0, 0, 0);
        }
        __builtin_amdgcn_s_setprio(0);
        __builtin_amdgcn_s_barrier();

        slR = (slR == 2) ? 0 : slR + 1;
        slS = (slS == 2) ? 0 : slS + 1;
    }

    // ---- epilogue: bias add + per-wave LDS transpose + coalesced nt dwordx4 stores ----
    float bv[4];
    #pragma unroll
    for (int ni = 0; ni < 4; ++ni) {
        const int col = bn0 + wc + ni * 16 + rA;
        bv[ni] = (col < N) ? bias[col] : 0.f;
    }
    float* lt = (float*)smem + wid * 2048;   // 8 waves x 8KB = 64KB <= 72KB (ring is dead)
    #pragma unroll
    for (int half = 0; half < 2; ++half) {
        #pragma unroll
        for (int mi2 = 0; mi2 < 2; ++mi2) {
            const int mi = half * 2 + mi2;
            #pragma unroll
            for (int ni = 0; ni < 4; ++ni) {
                #pragma unroll
                for (int r = 0; r < 4; ++r) {
                    const int row = mi2 * 16 + ks * 4 + r;              // 0..31
                    const int col = ni * 16 + rA;                       // 0..63
                    const int s = ((((row >> 2) & 3) ^ (row & 3)) << 4);
                    lt[row * 64 + (col ^ s)] = acc[mi][ni][r] + bv[ni];
                }
            }
        }
        #pragma unroll
        for (int i = 0; i < 8; ++i) {
            const int row = i * 4 + ks;                                 // 0..31
            const int c0 = rA * 4;
            const int s = ((((row >> 2) & 3) ^ (row & 3)) << 4);
            f32x4 v = *(const f32x4*)&lt[row * 64 + (c0 ^ s)];
            const int rowg = bm0 + wr + half * 32 + row;
            const int colg = bn0 + wc + c0;
            if (colg < N)   // N%4==0 so c0<N implies c0+3<N
                __builtin_nontemporal_store(v, (f32x4*)&out[(size_t)rowg * N + colg]);
        }
    }
}

extern "C" void kernel_launch(void* const* d_in, const int* in_sizes, int n_in,
                              void* d_out, int out_size, void* d_ws, size_t ws_size,
                              hipStream_t stream)
{
    const float* x   = (const float*)d_in[0];
    const float* hid = (const float*)d_in[1];
    const float* cel = (const float*)d_in[2];
    const float* V   = (const float*)d_in[3];
    const float* Wv  = (const float*)d_in[4];
    const float* Wg  = (const float*)d_in[5];
    const float* Ws  = (const float*)d_in[6];
    const float* wh  = (const float*)d_in[7];
    const float* Wx  = (const float*)d_in[8];
    const float* Wsh = (const float*)d_in[9];
    const float* Wm  = (const float*)d_in[10];
    const float* bm  = (const float*)d_in[11];

    float* out_o   = (float*)d_out;
    float* alpha_o = out_o + (size_t)BTT * NV;
    float* beta_o  = alpha_o + (size_t)BTT * KA;

    char* p = (char*)d_ws;
    bf16* sentb = (bf16*)p; p += (size_t)BTT * HH * 2;
    bf16* chb   = (bf16*)p; p += (size_t)BTT * HH * 2;
    bf16* xb    = (bf16*)p; p += (size_t)BTT * EE * 2;
    bf16* hb    = (bf16*)p; p += (size_t)BTT * HH * 2;
    bf16* Vb    = (bf16*)p; p += (size_t)BB * KA * HH * 2;
    bf16* Wxb   = (bf16*)p; p += (size_t)HH * EE * 2;
    bf16* Wshb  = (bf16*)p; p += (size_t)HH * HH * 2;
    bf16* Wmb   = (bf16*)p; p += (size_t)NV * HH * 2;
    bf16* Wvb   = (bf16*)p; p += (size_t)KA * HH * 2;
    bf16* Wgb   = (bf16*)p; p += (size_t)KA * HH * 2;
    bf16* Wsb   = (bf16*)p; p += (size_t)KA * HH * 2;
    bf16* zbuf  = (bf16*)p; p += 1024 * 2;
    float* cv   = (float*)p; p += (size_t)BB * KA * KA * 4;
    float* cg   = (float*)p; p += (size_t)BTT * KA * 4;

    prep_kernel<<<2048, 256, 0, stream>>>(x, hid, V, Wv, Wg, Ws, Wx, Wsh,
                                          xb, hb, Vb, Wvb, Wgb, Wsb, Wxb, Wshb, zbuf);

    // gate (256) + cv (49) + cg (64) + Wm-convert (143) = 512 blocks, all co-resident
    gate_mid128<<<512, 256, 0, stream>>>(xb, Wxb, Wshb, cel, sentb,
                                         Vb, Wvb, hb, Wgb, cv, cg, Wm, Wmb, zbuf);

    // fused cs (MFMA) + z/softmax + cch: replaces cs128 + softz + cch
    fused_mid<<<256, 256, 0, stream>>>(cv, cg, wh, sentb, Wsb, Vb, hid,
                                       alpha_o, beta_o, chb);

    // output = ch@Wm^T + bm   (256x128 tiles, ring-3, 2 blocks/CU, transposed nt stores)
    gemm256x128_bias<<<32 * 79, 512, 0, stream>>>(chb, Wmb, bm, out_o);
}

// Round 5
// 217.599 us; speedup vs baseline: 1.1036x; 1.1036x over previous
//
#include <hip/hip_runtime.h>
#include <hip/hip_bf16.h>
#include <math.h>

typedef __bf16 bf16;
typedef __bf16 bf16x4 __attribute__((ext_vector_type(4)));
typedef __bf16 bf16x8 __attribute__((ext_vector_type(8)));
typedef float f32x4 __attribute__((ext_vector_type(4)));

#define BB  128
#define TT  64
#define BTT 8192
#define HH  512
#define EE  1024
#define KA  49
#define NV  10000

__device__ __forceinline__ float ftanh(float x) {
    float cx = fminf(fmaxf(x, -15.f), 15.f);
    float e = __expf(2.f * cx);
    return (e - 1.f) * __builtin_amdgcn_rcpf(e + 1.f);
}
__device__ __forceinline__ float fsigmoid(float x) {
    return __builtin_amdgcn_rcpf(1.f + __expf(-x));
}

// ---------------- fused converts (one pass, float4 -> bf16x4) ----------------
__device__ __forceinline__ void cvt4(const float* __restrict__ s, bf16* __restrict__ d) {
    f32x4 v = *(const f32x4*)s;
    bf16x4 o = { (bf16)v[0], (bf16)v[1], (bf16)v[2], (bf16)v[3] };
    *(bf16x4*)d = o;
}
// nt variant: single-use f32 source, evict-first so bf16 working set stays in L2
__device__ __forceinline__ void cvt4nt(const float* __restrict__ s, bf16* __restrict__ d) {
    f32x4 v = __builtin_nontemporal_load((const f32x4*)s);
    bf16x4 o = { (bf16)v[0], (bf16)v[1], (bf16)v[2], (bf16)v[3] };
    *(bf16x4*)d = o;
}

// Wm handled by filler blocks in gate_mid128; hpb eliminated (shifted-hb staging + zero page).
__global__ __launch_bounds__(256)
void prep_kernel(const float* __restrict__ x, const float* __restrict__ hid,
                 const float* __restrict__ V, const float* __restrict__ Wv,
                 const float* __restrict__ Wg, const float* __restrict__ Ws,
                 const float* __restrict__ Wx, const float* __restrict__ Wsh,
                 bf16* __restrict__ xb, bf16* __restrict__ hb,
                 bf16* __restrict__ Vb, bf16* __restrict__ Wvb, bf16* __restrict__ Wgb,
                 bf16* __restrict__ Wsb, bf16* __restrict__ Wxb, bf16* __restrict__ Wshb,
                 bf16* __restrict__ zbuf)
{
    if (blockIdx.x == 0 && threadIdx.x < 128) {   // 1024-elem zero page for hprev t==0 rows
        bf16x8 z = {};
        *(bf16x8*)(zbuf + threadIdx.x * 8) = z;
    }

    const long NX = (long)BTT * EE;
    const long NH = (long)BTT * HH;
    const long NVV = (long)BB * KA * HH;
    const long NWX = (long)HH * EE;
    const long NWSH = (long)HH * HH;
    const long NW = (long)KA * HH;
    const long total4 = (NX + NH + NVV + NWX + NWSH + 3 * NW) >> 2;

    long t0 = (long)blockIdx.x * 256 + threadIdx.x;
    long st = (long)gridDim.x * 256;
    for (long i4 = t0; i4 < total4; i4 += st) {
        long i = i4 << 2;
        if (i < NX) { cvt4nt(x + i, xb + i); continue; }
        i -= NX;
        if (i < NH) { cvt4(hid + i, hb + i); continue; }
        i -= NH;
        if (i < NVV) { cvt4nt(V + i, Vb + i); continue; }
        i -= NVV;
        if (i < NWX) { cvt4nt(Wx + i, Wxb + i); continue; }
        i -= NWX;
        if (i < NWSH) { cvt4nt(Wsh + i, Wshb + i); continue; }
        i -= NWSH;
        if (i < NW) { cvt4nt(Wv + i, Wvb + i); continue; }
        i -= NW;
        if (i < NW) { cvt4nt(Wg + i, Wgb + i); continue; }
        i -= NW;
        cvt4nt(Ws + i, Wsb + i);
    }
}

// ---------------- pipelined 128x128 GEMM core (ring-4 BK=32, lookahead-3, counted vmcnt) ----
// C = A1@B1^T (+ A2@B2^T), row-major bf16, K-contiguous. 4 waves (2x2), wave = 64x64.
// SHIFT: A2 rows read shifted down by one (row r reads A2 row r-1; rows r%64==0 read zbuf).
// EPI 0: sentb[r,c] = bf16(sigmoid(acc)*tanh(eaux[r*ldo+c]))
// EPI 2: ((float*)out)[r*ldo+c] = acc   (masked c < N)
template<int EPI, bool SHIFT>
__device__ __forceinline__ void gemm128_core(
    bf16* smem,
    const bf16* __restrict__ A1, const bf16* __restrict__ B1, int K1,
    const bf16* __restrict__ A2, const bf16* __restrict__ B2, int K2,
    int N, const float* __restrict__ eaux, void* __restrict__ outv, int ldo,
    int bm0, int bn0, const bf16* __restrict__ zbuf)
{
    const int tid = threadIdx.x;
    const int lane = tid & 63;
    const int wid = tid >> 6;
    const int wm = (wid >> 1) * 64;
    const int wn = (wid & 1) * 64;
    const int rA = lane & 15;
    const int ks = lane >> 4;
    const int swzB = (ks ^ ((rA >> 1) & 3)) * 16;   // frag-read byte slot (row-swizzle)

    // staging: 512 16B-chunks per 8KB matrix tile; thread covers chunks c0, c1
    const int c0 = tid, c1 = tid + 256;
    const int row0 = c0 >> 2, row1 = c1 >> 2;
    const int gc0 = ((c0 & 3) ^ ((row0 >> 1) & 3)) * 8;  // pre-swizzled global col (elems)
    const int gc1 = ((c1 & 3) ^ ((row1 >> 1) & 3)) * 8;
    const int br0 = (bn0 + row0 < N) ? bn0 + row0 : N - 1;
    const int br1 = (bn0 + row1 < N) ? bn0 + row1 : N - 1;

    const int NT1 = K1 >> 5;
    const int NT2 = K2 >> 5;
    const int NT = NT1 + NT2;

    // hoisted per-row source pointers
    const bf16* A1r0 = A1 + (size_t)(bm0 + row0) * K1 + gc0;
    const bf16* A1r1 = A1 + (size_t)(bm0 + row1) * K1 + gc1;
    const bf16* B1r0 = B1 + (size_t)br0 * K1 + gc0;
    const bf16* B1r1 = B1 + (size_t)br1 * K1 + gc1;
    const bf16 *A2r0 = nullptr, *A2r1 = nullptr, *B2r0 = nullptr, *B2r1 = nullptr;
    if (K2 > 0) {
        if (SHIFT) {
            A2r0 = (((bm0 + row0) & 63) == 0) ? zbuf + gc0
                                              : A2 + (size_t)(bm0 + row0 - 1) * K2 + gc0;
            A2r1 = (((bm0 + row1) & 63) == 0) ? zbuf + gc1
                                              : A2 + (size_t)(bm0 + row1 - 1) * K2 + gc1;
        } else {
            A2r0 = A2 + (size_t)(bm0 + row0) * K2 + gc0;
            A2r1 = A2 + (size_t)(bm0 + row1) * K2 + gc1;
        }
        B2r0 = B2 + (size_t)br0 * K2 + gc0;
        B2r1 = B2 + (size_t)br1 * K2 + gc1;
    }

    auto stage = [&](int t) {
        const bf16 *a0, *a1, *b0, *b1; int k0;
        if (t < NT1) { k0 = t << 5;          a0 = A1r0; a1 = A1r1; b0 = B1r0; b1 = B1r1; }
        else         { k0 = (t - NT1) << 5;  a0 = A2r0; a1 = A2r1; b0 = B2r0; b1 = B2r1; }
        char* base = (char*)smem + (t & 3) * 16384;
        __builtin_amdgcn_global_load_lds(
            (const __attribute__((address_space(1))) unsigned int*)(a0 + k0),
            (__attribute__((address_space(3))) unsigned int*)(base + c0 * 16), 16, 0, 0);
        __builtin_amdgcn_global_load_lds(
            (const __attribute__((address_space(1))) unsigned int*)(a1 + k0),
            (__attribute__((address_space(3))) unsigned int*)(base + c1 * 16), 16, 0, 0);
        __builtin_amdgcn_global_load_lds(
            (const __attribute__((address_space(1))) unsigned int*)(b0 + k0),
            (__attribute__((address_space(3))) unsigned int*)(base + 8192 + c0 * 16), 16, 0, 0);
        __builtin_amdgcn_global_load_lds(
            (const __attribute__((address_space(1))) unsigned int*)(b1 + k0),
            (__attribute__((address_space(3))) unsigned int*)(base + 8192 + c1 * 16), 16, 0, 0);
    };

    f32x4 acc[4][4] = {};

    // prologue: tiles 0,1,2 (12 loads/thread); vmcnt(8) -> tile 0 landed
    stage(0); stage(1); stage(2);
    asm volatile("s_waitcnt vmcnt(8)" ::: "memory");
    __builtin_amdgcn_s_barrier();

    for (int t = 0; t < NT; ++t) {
        const char* sA = (const char*)smem + (t & 3) * 16384;
        const char* sB = sA + 8192;

        bf16x8 af[4], bfr[4];
        #pragma unroll
        for (int mi = 0; mi < 4; ++mi)
            af[mi] = *(const bf16x8*)(sA + (wm + mi * 16 + rA) * 64 + swzB);
        #pragma unroll
        for (int ni = 0; ni < 4; ++ni)
            bfr[ni] = *(const bf16x8*)(sB + (wn + ni * 16 + rA) * 64 + swzB);

        if (t + 3 < NT) {
            stage(t + 3);                                    // 12 outstanding
            asm volatile("s_waitcnt vmcnt(8)" ::: "memory"); // tile t+1 landed
        } else if (t + 2 < NT) {
            asm volatile("s_waitcnt vmcnt(4)" ::: "memory"); // tile t+1 landed
        } else {
            asm volatile("s_waitcnt vmcnt(0)" ::: "memory");
        }
        __builtin_amdgcn_s_barrier();

        __builtin_amdgcn_s_setprio(1);
        #pragma unroll
        for (int mi = 0; mi < 4; ++mi) {
            #pragma unroll
            for (int ni = 0; ni < 4; ++ni)
                acc[mi][ni] = __builtin_amdgcn_mfma_f32_16x16x32_bf16(af[mi], bfr[ni], acc[mi][ni], 0, 0, 0);
        }
        __builtin_amdgcn_s_setprio(0);
        __builtin_amdgcn_s_barrier();
    }

    // C/D layout: col = lane&15, row = (lane>>4)*4 + reg
    #pragma unroll
    for (int mi = 0; mi < 4; ++mi) {
        #pragma unroll
        for (int ni = 0; ni < 4; ++ni) {
            const int col = bn0 + wn + ni * 16 + rA;
            if (col < N) {
                #pragma unroll
                for (int r = 0; r < 4; ++r) {
                    const int rowg = bm0 + wm + mi * 16 + ks * 4 + r;
                    float v = acc[mi][ni][r];
                    if (EPI == 0) {
                        ((bf16*)outv)[(size_t)rowg * ldo + col] =
                            (bf16)(fsigmoid(v) * ftanh(eaux[(size_t)rowg * ldo + col]));
                    } else {
                        ((float*)outv)[(size_t)rowg * ldo + col] = v;
                    }
                }
            }
        }
    }
}

// merged launch: gate (256) + cv (49) + cg (64) + Wm-convert filler (143) = 512 blocks
__global__ __launch_bounds__(256, 2)
void gate_mid128(const bf16* __restrict__ xb, const bf16* __restrict__ Wxb,
                 const bf16* __restrict__ Wshb,
                 const float* __restrict__ cel, bf16* __restrict__ sentb,
                 const bf16* __restrict__ Vb, const bf16* __restrict__ Wvb,
                 const bf16* __restrict__ hb, const bf16* __restrict__ Wgb,
                 float* __restrict__ cv, float* __restrict__ cg,
                 const float* __restrict__ Wm, bf16* __restrict__ Wmb,
                 const bf16* __restrict__ zbuf)
{
    __shared__ bf16 smem[4 * 8192];
    const int bid = blockIdx.x;
    if (bid >= 369) {
        const long n4 = ((long)NV * HH) >> 2;
        for (long i4 = (long)(bid - 369) * 256 + threadIdx.x; i4 < n4; i4 += 143L * 256)
            cvt4nt(Wm + (i4 << 2), Wmb + (i4 << 2));
        return;
    }
    if (bid < 256) {
        const int bm0 = (bid >> 2) * 128;
        const int bn0 = (bid & 3) * 128;
        // gate = x@Wx^T + hprev@Wsh^T, hprev = hb shifted one row (zero at t==0)
        gemm128_core<0, true>(smem, xb, Wxb, EE, hb, Wshb, HH, HH, cel, (void*)sentb, HH,
                              bm0, bn0, zbuf);
    } else if (bid < 305) {
        gemm128_core<2, false>(smem, Vb, Wvb, HH, nullptr, nullptr, 0, KA, nullptr,
                               (void*)cv, KA, (bid - 256) * 128, 0, nullptr);
    } else {
        gemm128_core<2, false>(smem, hb, Wgb, HH, nullptr, nullptr, 0, KA, nullptr,
                               (void*)cg, KA, (bid - 305) * 128, 0, nullptr);
    }
}

// ---------------- cs64: cs_partial = sent@Ws^T (K=512 only; cg added in softz) ----------
// 128 blocks x 64-row M-tiles (2x the coverage of the old 64-block version, half the work:
// the h@Wg^T segment is dropped since cg is already computed by gate_mid128).
// 4 waves, wave w owns cols w*16..w*16+15. Ring-4 BK=32, lookahead-3, uniform 2 loads/thread.
__global__ __launch_bounds__(256, 2)
void cs64(const bf16* __restrict__ sentb, const bf16* __restrict__ Wsb,
          float* __restrict__ cs)
{
    __shared__ bf16 smem[4 * 4096];   // ring: 4 slots x (A 4KB | B 4KB) = 32 KB
    const int bm0 = blockIdx.x * 64;
    const int tid = threadIdx.x;
    const int lane = tid & 63;
    const int w = tid >> 6;
    const int rA = lane & 15;
    const int ks = lane >> 4;
    const int swzB = (ks ^ ((rA >> 1) & 3)) * 16;

    // staging: A 256 chunks (1/thread), B 256 chunks (1/thread); same swizzle as core
    const int row = tid >> 2;               // 0..63
    const int gc = ((tid & 3) ^ ((row >> 1) & 3)) * 8;
    const int browc = (row < KA) ? row : KA - 1;
    const bf16* Ar = sentb + (size_t)(bm0 + row) * HH + gc;
    const bf16* Br = Wsb + (size_t)browc * HH + gc;

    auto stage = [&](int t) {
        char* base = (char*)smem + (t & 3) * 8192;
        const int k0 = t << 5;
        __builtin_amdgcn_global_load_lds(
            (const __attribute__((address_space(1))) unsigned int*)(Ar + k0),
            (__attribute__((address_space(3))) unsigned int*)(base + tid * 16), 16, 0, 0);
        __builtin_amdgcn_global_load_lds(
            (const __attribute__((address_space(1))) unsigned int*)(Br + k0),
            (__attribute__((address_space(3))) unsigned int*)(base + 4096 + tid * 16), 16, 0, 0);
    };

    f32x4 acc[4] = {};
    const int NT = HH / 32;   // 16

    // prologue: tiles 0,1,2 (6 loads/thread); vmcnt(4) -> tile 0 landed
    stage(0); stage(1); stage(2);
    asm volatile("s_waitcnt vmcnt(4)" ::: "memory");
    __builtin_amdgcn_s_barrier();

    for (int t = 0; t < NT; ++t) {
        const char* sA = (const char*)smem + (t & 3) * 8192;
        const char* sB = sA + 4096;

        bf16x8 af[4];
        #pragma unroll
        for (int mi = 0; mi < 4; ++mi)
            af[mi] = *(const bf16x8*)(sA + (mi * 16 + rA) * 64 + swzB);
        bf16x8 bfr = *(const bf16x8*)(sB + (w * 16 + rA) * 64 + swzB);

        if (t + 3 < NT) {
            stage(t + 3);                                    // 6 outstanding
            asm volatile("s_waitcnt vmcnt(4)" ::: "memory"); // tile t+1 landed
        } else if (t + 2 < NT) {
            asm volatile("s_waitcnt vmcnt(2)" ::: "memory");
        } else {
            asm volatile("s_waitcnt vmcnt(0)" ::: "memory");
        }
        __builtin_amdgcn_s_barrier();

        __builtin_amdgcn_s_setprio(1);
        #pragma unroll
        for (int mi = 0; mi < 4; ++mi)
            acc[mi] = __builtin_amdgcn_mfma_f32_16x16x32_bf16(af[mi], bfr, acc[mi], 0, 0, 0);
        __builtin_amdgcn_s_setprio(0);
        __builtin_amdgcn_s_barrier();
    }

    // C/D: col = lane&15 (+ w*16), row = ks*4 + r (+ mi*16)
    const int col = w * 16 + rA;
    if (col < KA) {
        #pragma unroll
        for (int mi = 0; mi < 4; ++mi) {
            #pragma unroll
            for (int r = 0; r < 4; ++r) {
                const int rowg = bm0 + mi * 16 + ks * 4 + r;
                cs[(size_t)rowg * KA + col] = acc[mi][r];
            }
        }
    }
}

// ---------------- z / alpha / beta (csv = cs_partial + cg; formula verified in R4) -------
__global__ __launch_bounds__(256)
void softz_kernel(const float* __restrict__ cv, const float* __restrict__ cg,
                  const float* __restrict__ cs, const float* __restrict__ wh,
                  float* __restrict__ alpha, float* __restrict__ beta)
{
    __shared__ float cvL[KA * KA];
    __shared__ float whL[64];
    __shared__ float cgL[4 * KA];

    const int tid = threadIdx.x;
    const int w = tid >> 6, lane = tid & 63;
    const int bt0 = blockIdx.x * 4;
    const int b = bt0 >> 6;
    const int bt = bt0 + w;

    const float* cvb = cv + (size_t)b * KA * KA;
    for (int i = tid; i < KA * KA; i += 256) cvL[i] = cvb[i];
    if (tid < KA) whL[tid] = wh[tid];
    if (lane < KA) cgL[w * KA + lane] = cg[(size_t)bt * KA + lane];
    float csv0 = (lane < KA) ? cs[(size_t)bt * KA + lane] : 0.f;
    __syncthreads();

    float z = -INFINITY;
    if (lane < KA) {
        const float* cvk = cvL + lane * KA;
        const float* cgr = cgL + w * KA;
        float acc = 0.f;
        #pragma unroll 7
        for (int n = 0; n < KA; ++n)
            acc += ftanh(cvk[n] + cgr[n]) * whL[n];
        z = acc;
    }
    const float csv = csv0 + ((lane < KA) ? cgL[w * KA + lane] : 0.f);
    float u = (lane < KA) ? ftanh(csv) * whL[lane] : 0.f;

    float m1 = z;
    #pragma unroll
    for (int o = 32; o; o >>= 1) m1 = fmaxf(m1, __shfl_xor(m1, o, 64));
    float e = (lane < KA) ? __expf(z - m1) : 0.f;
    float s1 = e, ze = u;
    #pragma unroll
    for (int o = 32; o; o >>= 1) { s1 += __shfl_xor(s1, o, 64); ze += __shfl_xor(ze, o, 64); }

    if (lane < KA) alpha[(size_t)bt * KA + lane] = e / s1;
    if (lane == 0) {
        float M2 = fmaxf(m1, ze);
        float denom = s1 * __expf(m1 - M2) + __expf(ze - M2);
        beta[bt] = __expf(ze - M2) / denom;
    }
}

// ---------------- c = alpha@V ; ch = beta*sent + (1-beta)*c + hiddens -> bf16 ----------------
__global__ __launch_bounds__(256)
void cch_kernel(const float* __restrict__ alpha, const float* __restrict__ beta,
                const bf16* __restrict__ Vb, const bf16* __restrict__ sentb,
                const float* __restrict__ hid, bf16* __restrict__ chb)
{
    __shared__ float aL[TT * KA];   // 12.25 KB
    __shared__ float bL[TT];

    const int b = blockIdx.x >> 3;
    const int hc = blockIdx.x & 7;
    const int tid = threadIdx.x;
    const int w = tid >> 6, lane = tid & 63;
    const int h = hc * 64 + lane;

    const float* ab = alpha + (size_t)b * TT * KA;
    for (int i = tid; i < TT * KA; i += 256) aL[i] = ab[i];
    if (tid < TT) bL[tid] = beta[b * TT + tid];

    float vreg[KA];
    #pragma unroll
    for (int k = 0; k < KA; ++k) vreg[k] = (float)Vb[((size_t)b * KA + k) * HH + h];
    __syncthreads();

    #pragma unroll 1
    for (int tt = 0; tt < 16; ++tt) {
        const int t = w * 16 + tt;
        const int bt = b * TT + t;
        const float* ar = aL + t * KA;
        float c = 0.f;
        #pragma unroll
        for (int k = 0; k < KA; ++k) c += ar[k] * vreg[k];
        const float be = bL[t];
        const size_t idx = (size_t)bt * HH + h;
        float ch = be * (float)sentb[idx] + (1.f - be) * c
                 + __builtin_nontemporal_load(hid + idx);
        chb[idx] = (bf16)ch;
    }
}

// ---------------- 256x128 deep-pipelined GEMM for the output projection ----------------
// M=8192, N=10000 (grid 32x79), K=512. BK=32, ring-3 LDS (72 KiB -> 2 blocks/CU),
// 8 waves (4Mx2N), lookahead-2 (vmcnt(3) steady state), raw s_barrier, setprio.
// Epilogue: per-wave LDS transpose -> fully-coalesced nontemporal dwordx4 stores.
__global__ __launch_bounds__(512, 4)
void gemm256x128_bias(const bf16* __restrict__ A, const bf16* __restrict__ B,
                      const float* __restrict__ bias, float* __restrict__ out)
{
    const int K = HH;        // 512
    const int N = NV;        // 10000
    const int NT = K / 32;   // 16
    const int ntn = 79;      // ceil(10000/128)

    __shared__ bf16 smem[3 * 12288];   // ring slot: [A 16KB][B 8KB] = 24 KB

    // XCD-bijective swizzle (nwg = 2528, 2528/8 = 316)
    const int bid = blockIdx.x;
    const int wg = (bid & 7) * 316 + (bid >> 3);
    const int bm0 = (wg / ntn) * 256;
    const int bn0 = (wg % ntn) * 128;

    const int tid = threadIdx.x;
    const int lane = tid & 63;
    const int wid = tid >> 6;
    const int wr = (wid >> 1) * 64;   // 4 M-waves
    const int wc = (wid & 1) * 64;    // 2 N-waves
    const int rA = lane & 15;
    const int ks = lane >> 4;
    const int swz = (ks ^ ((rA >> 1) & 3)) * 16;

    // staging: A 1024 chunks (2/thread), B 512 chunks (1/thread)
    const int arow0 = tid >> 2;             // 0..127
    const int arow1 = arow0 + 128;          // 128..255
    const int gcA0 = ((tid & 3) ^ ((arow0 >> 1) & 3)) * 8;
    const int gcA1 = ((tid & 3) ^ ((arow1 >> 1) & 3)) * 8;
    const int brow = tid >> 2;              // 0..127
    const int gcB  = ((tid & 3) ^ ((brow >> 1) & 3)) * 8;
    const int browc = (bn0 + brow < N) ? bn0 + brow : N - 1;

    const bf16* Ap0 = A + (size_t)(bm0 + arow0) * K + gcA0;
    const bf16* Ap1 = A + (size_t)(bm0 + arow1) * K + gcA1;
    const bf16* Bp  = B + (size_t)browc * K + gcB;

    auto stage = [&](int t, int slot) {
        char* base = (char*)smem + slot * 24576;
        const int k0 = t << 5;
        __builtin_amdgcn_global_load_lds(
            (const __attribute__((address_space(1))) unsigned int*)(Ap0 + k0),
            (__attribute__((address_space(3))) unsigned int*)(base + tid * 16), 16, 0, 0);
        __builtin_amdgcn_global_load_lds(
            (const __attribute__((address_space(1))) unsigned int*)(Ap1 + k0),
            (__attribute__((address_space(3))) unsigned int*)(base + (tid + 512) * 16), 16, 0, 0);
        __builtin_amdgcn_global_load_lds(
            (const __attribute__((address_space(1))) unsigned int*)(Bp + k0),
            (__attribute__((address_space(3))) unsigned int*)(base + 16384 + tid * 16), 16, 0, 0);
    };

    f32x4 acc[4][4] = {};

    // prologue: tiles 0,1 into slots 0,1 (6 loads/thread); vmcnt(3) -> tile 0 landed
    stage(0, 0); stage(1, 1);
    asm volatile("s_waitcnt vmcnt(3)" ::: "memory");
    __builtin_amdgcn_s_barrier();

    int slR = 0, slS = 2;
    for (int t = 0; t < NT; ++t) {
        const char* sA = (const char*)smem + slR * 24576;
        const char* sB = sA + 16384;

        bf16x8 af[4], bfr[4];
        #pragma unroll
        for (int mi = 0; mi < 4; ++mi)
            af[mi] = *(const bf16x8*)(sA + (wr + mi * 16 + rA) * 64 + swz);
        #pragma unroll
        for (int ni = 0; ni < 4; ++ni)
            bfr[ni] = *(const bf16x8*)(sB + (wc + ni * 16 + rA) * 64 + swz);

        if (t + 2 < NT) {
            stage(t + 2, slS);                               // 6 outstanding
            asm volatile("s_waitcnt vmcnt(3)" ::: "memory"); // tile t+1 landed
        } else {
            asm volatile("s_waitcnt vmcnt(0)" ::: "memory");
        }
        __builtin_amdgcn_s_barrier();

        __builtin_amdgcn_s_setprio(1);
        #pragma unroll
        for (int mi = 0; mi < 4; ++mi) {
            #pragma unroll
            for (int ni = 0; ni < 4; ++ni)
                acc[mi][ni] = __builtin_amdgcn_mfma_f32_16x16x32_bf16(af[mi], bfr[ni], acc[mi][ni], 0, 0, 0);
        }
        __builtin_amdgcn_s_setprio(0);
        __builtin_amdgcn_s_barrier();

        slR = (slR == 2) ? 0 : slR + 1;
        slS = (slS == 2) ? 0 : slS + 1;
    }

    // ---- epilogue: bias add + per-wave LDS transpose + coalesced nt dwordx4 stores ----
    float bv[4];
    #pragma unroll
    for (int ni = 0; ni < 4; ++ni) {
        const int col = bn0 + wc + ni * 16 + rA;
        bv[ni] = (col < N) ? bias[col] : 0.f;
    }
    float* lt = (float*)smem + wid * 2048;   // 8 waves x 8KB = 64KB <= 72KB (ring is dead)
    #pragma unroll
    for (int half = 0; half < 2; ++half) {
        #pragma unroll
        for (int mi2 = 0; mi2 < 2; ++mi2) {
            const int mi = half * 2 + mi2;
            #pragma unroll
            for (int ni = 0; ni < 4; ++ni) {
                #pragma unroll
                for (int r = 0; r < 4; ++r) {
                    const int row = mi2 * 16 + ks * 4 + r;              // 0..31
                    const int col = ni * 16 + rA;                       // 0..63
                    const int s = ((((row >> 2) & 3) ^ (row & 3)) << 4);
                    lt[row * 64 + (col ^ s)] = acc[mi][ni][r] + bv[ni];
                }
            }
        }
        #pragma unroll
        for (int i = 0; i < 8; ++i) {
            const int row = i * 4 + ks;                                 // 0..31
            const int c0 = rA * 4;
            const int s = ((((row >> 2) & 3) ^ (row & 3)) << 4);
            f32x4 v = *(const f32x4*)&lt[row * 64 + (c0 ^ s)];
            const int rowg = bm0 + wr + half * 32 + row;
            const int colg = bn0 + wc + c0;
            if (colg < N)   // N%4==0 so c0<N implies c0+3<N
                __builtin_nontemporal_store(v, (f32x4*)&out[(size_t)rowg * N + colg]);
        }
    }
}

extern "C" void kernel_launch(void* const* d_in, const int* in_sizes, int n_in,
                              void* d_out, int out_size, void* d_ws, size_t ws_size,
                              hipStream_t stream)
{
    const float* x   = (const float*)d_in[0];
    const float* hid = (const float*)d_in[1];
    const float* cel = (const float*)d_in[2];
    const float* V   = (const float*)d_in[3];
    const float* Wv  = (const float*)d_in[4];
    const float* Wg  = (const float*)d_in[5];
    const float* Ws  = (const float*)d_in[6];
    const float* wh  = (const float*)d_in[7];
    const float* Wx  = (const float*)d_in[8];
    const float* Wsh = (const float*)d_in[9];
    const float* Wm  = (const float*)d_in[10];
    const float* bm  = (const float*)d_in[11];

    float* out_o   = (float*)d_out;
    float* alpha_o = out_o + (size_t)BTT * NV;
    float* beta_o  = alpha_o + (size_t)BTT * KA;

    char* p = (char*)d_ws;
    bf16* sentb = (bf16*)p; p += (size_t)BTT * HH * 2;
    bf16* chb   = (bf16*)p; p += (size_t)BTT * HH * 2;
    bf16* xb    = (bf16*)p; p += (size_t)BTT * EE * 2;
    bf16* hb    = (bf16*)p; p += (size_t)BTT * HH * 2;
    bf16* Vb    = (bf16*)p; p += (size_t)BB * KA * HH * 2;
    bf16* Wxb   = (bf16*)p; p += (size_t)HH * EE * 2;
    bf16* Wshb  = (bf16*)p; p += (size_t)HH * HH * 2;
    bf16* Wmb   = (bf16*)p; p += (size_t)NV * HH * 2;
    bf16* Wvb   = (bf16*)p; p += (size_t)KA * HH * 2;
    bf16* Wgb   = (bf16*)p; p += (size_t)KA * HH * 2;
    bf16* Wsb   = (bf16*)p; p += (size_t)KA * HH * 2;
    bf16* zbuf  = (bf16*)p; p += 1024 * 2;
    float* cv   = (float*)p; p += (size_t)BB * KA * KA * 4;
    float* cg   = (float*)p; p += (size_t)BTT * KA * 4;
    float* cs   = (float*)p; p += (size_t)BTT * KA * 4;

    prep_kernel<<<2048, 256, 0, stream>>>(x, hid, V, Wv, Wg, Ws, Wx, Wsh,
                                          xb, hb, Vb, Wvb, Wgb, Wsb, Wxb, Wshb, zbuf);

    // gate (256) + cv (49) + cg (64) + Wm-convert (143) = 512 blocks, all co-resident
    gate_mid128<<<512, 256, 0, stream>>>(xb, Wxb, Wshb, cel, sentb,
                                         Vb, Wvb, hb, Wgb, cv, cg, Wm, Wmb, zbuf);

    // cs_partial = sent@Ws^T only (cg added in softz); 128 blocks, 64-row tiles
    cs64<<<128, 256, 0, stream>>>(sentb, Wsb, cs);

    softz_kernel<<<BTT / 4, 256, 0, stream>>>(cv, cg, cs, wh, alpha_o, beta_o);
    cch_kernel<<<BB * 8, 256, 0, stream>>>(alpha_o, beta_o, Vb, sentb, hid, chb);

    // output = ch@Wm^T + bm   (256x128 tiles, ring-3, 2 blocks/CU, transposed nt stores)
    gemm256x128_bias<<<32 * 79, 512, 0, stream>>>(chb, Wmb, bm, out_o);
}

// Round 6
// 206.010 us; speedup vs baseline: 1.1657x; 1.0563x over previous
//
#include <hip/hip_runtime.h>
#include <hip/hip_bf16.h>
#include <math.h>

typedef __bf16 bf16;
typedef __bf16 bf16x4 __attribute__((ext_vector_type(4)));
typedef __bf16 bf16x8 __attribute__((ext_vector_type(8)));
typedef float f32x4 __attribute__((ext_vector_type(4)));

#define BB  128
#define TT  64
#define BTT 8192
#define HH  512
#define EE  1024
#define KA  49
#define NV  10000

__device__ __forceinline__ float ftanh(float x) {
    float cx = fminf(fmaxf(x, -15.f), 15.f);
    float e = __expf(2.f * cx);
    return (e - 1.f) * __builtin_amdgcn_rcpf(e + 1.f);
}
__device__ __forceinline__ float fsigmoid(float x) {
    return __builtin_amdgcn_rcpf(1.f + __expf(-x));
}

// ---------------- fused converts (one pass, float4 -> bf16x4) ----------------
__device__ __forceinline__ void cvt4(const float* __restrict__ s, bf16* __restrict__ d) {
    f32x4 v = *(const f32x4*)s;
    bf16x4 o = { (bf16)v[0], (bf16)v[1], (bf16)v[2], (bf16)v[3] };
    *(bf16x4*)d = o;
}
// nt variant: single-use f32 source, evict-first so bf16 working set stays in L2
__device__ __forceinline__ void cvt4nt(const float* __restrict__ s, bf16* __restrict__ d) {
    f32x4 v = __builtin_nontemporal_load((const f32x4*)s);
    bf16x4 o = { (bf16)v[0], (bf16)v[1], (bf16)v[2], (bf16)v[3] };
    *(bf16x4*)d = o;
}

// x pass removed entirely (gate stages x f32 directly). Wm handled by gate_mid filler.
__global__ __launch_bounds__(256)
void prep_kernel(const float* __restrict__ hid,
                 const float* __restrict__ V, const float* __restrict__ Wv,
                 const float* __restrict__ Wg, const float* __restrict__ Ws,
                 const float* __restrict__ Wx, const float* __restrict__ Wsh,
                 bf16* __restrict__ hb,
                 bf16* __restrict__ Vb, bf16* __restrict__ Wvb, bf16* __restrict__ Wgb,
                 bf16* __restrict__ Wsb, bf16* __restrict__ Wxb, bf16* __restrict__ Wshb,
                 bf16* __restrict__ zbuf)
{
    if (blockIdx.x == 0 && threadIdx.x < 128) {   // 1024-elem zero page for hprev t==0 rows
        bf16x8 z = {};
        *(bf16x8*)(zbuf + threadIdx.x * 8) = z;
    }

    const long NH = (long)BTT * HH;
    const long NVV = (long)BB * KA * HH;
    const long NWX = (long)HH * EE;
    const long NWSH = (long)HH * HH;
    const long NW = (long)KA * HH;
    const long total4 = (NH + NVV + NWX + NWSH + 3 * NW) >> 2;

    long t0 = (long)blockIdx.x * 256 + threadIdx.x;
    long st = (long)gridDim.x * 256;
    for (long i4 = t0; i4 < total4; i4 += st) {
        long i = i4 << 2;
        if (i < NH) { cvt4(hid + i, hb + i); continue; }
        i -= NH;
        if (i < NVV) { cvt4nt(V + i, Vb + i); continue; }
        i -= NVV;
        if (i < NWX) { cvt4nt(Wx + i, Wxb + i); continue; }
        i -= NWX;
        if (i < NWSH) { cvt4nt(Wsh + i, Wshb + i); continue; }
        i -= NWSH;
        if (i < NW) { cvt4nt(Wv + i, Wvb + i); continue; }
        i -= NW;
        if (i < NW) { cvt4nt(Wg + i, Wgb + i); continue; }
        i -= NW;
        cvt4nt(Ws + i, Wsb + i);
    }
}

// ---------------- pipelined 128x128 GEMM core (ring-4 BK=32, lookahead-3, counted vmcnt) ----
// (unchanged, used by cv/cg branches)
template<int EPI, bool SHIFT>
__device__ __forceinline__ void gemm128_core(
    bf16* smem,
    const bf16* __restrict__ A1, const bf16* __restrict__ B1, int K1,
    const bf16* __restrict__ A2, const bf16* __restrict__ B2, int K2,
    int N, const float* __restrict__ eaux, void* __restrict__ outv, int ldo,
    int bm0, int bn0, const bf16* __restrict__ zbuf)
{
    const int tid = threadIdx.x;
    const int lane = tid & 63;
    const int wid = tid >> 6;
    const int wm = (wid >> 1) * 64;
    const int wn = (wid & 1) * 64;
    const int rA = lane & 15;
    const int ks = lane >> 4;
    const int swzB = (ks ^ ((rA >> 1) & 3)) * 16;

    const int c0 = tid, c1 = tid + 256;
    const int row0 = c0 >> 2, row1 = c1 >> 2;
    const int gc0 = ((c0 & 3) ^ ((row0 >> 1) & 3)) * 8;
    const int gc1 = ((c1 & 3) ^ ((row1 >> 1) & 3)) * 8;
    const int br0 = (bn0 + row0 < N) ? bn0 + row0 : N - 1;
    const int br1 = (bn0 + row1 < N) ? bn0 + row1 : N - 1;

    const int NT1 = K1 >> 5;
    const int NT2 = K2 >> 5;
    const int NT = NT1 + NT2;

    const bf16* A1r0 = A1 + (size_t)(bm0 + row0) * K1 + gc0;
    const bf16* A1r1 = A1 + (size_t)(bm0 + row1) * K1 + gc1;
    const bf16* B1r0 = B1 + (size_t)br0 * K1 + gc0;
    const bf16* B1r1 = B1 + (size_t)br1 * K1 + gc1;
    const bf16 *A2r0 = nullptr, *A2r1 = nullptr, *B2r0 = nullptr, *B2r1 = nullptr;
    if (K2 > 0) {
        if (SHIFT) {
            A2r0 = (((bm0 + row0) & 63) == 0) ? zbuf + gc0
                                              : A2 + (size_t)(bm0 + row0 - 1) * K2 + gc0;
            A2r1 = (((bm0 + row1) & 63) == 0) ? zbuf + gc1
                                              : A2 + (size_t)(bm0 + row1 - 1) * K2 + gc1;
        } else {
            A2r0 = A2 + (size_t)(bm0 + row0) * K2 + gc0;
            A2r1 = A2 + (size_t)(bm0 + row1) * K2 + gc1;
        }
        B2r0 = B2 + (size_t)br0 * K2 + gc0;
        B2r1 = B2 + (size_t)br1 * K2 + gc1;
    }

    auto stage = [&](int t) {
        const bf16 *a0, *a1, *b0, *b1; int k0;
        if (t < NT1) { k0 = t << 5;          a0 = A1r0; a1 = A1r1; b0 = B1r0; b1 = B1r1; }
        else         { k0 = (t - NT1) << 5;  a0 = A2r0; a1 = A2r1; b0 = B2r0; b1 = B2r1; }
        char* base = (char*)smem + (t & 3) * 16384;
        __builtin_amdgcn_global_load_lds(
            (const __attribute__((address_space(1))) unsigned int*)(a0 + k0),
            (__attribute__((address_space(3))) unsigned int*)(base + c0 * 16), 16, 0, 0);
        __builtin_amdgcn_global_load_lds(
            (const __attribute__((address_space(1))) unsigned int*)(a1 + k0),
            (__attribute__((address_space(3))) unsigned int*)(base + c1 * 16), 16, 0, 0);
        __builtin_amdgcn_global_load_lds(
            (const __attribute__((address_space(1))) unsigned int*)(b0 + k0),
            (__attribute__((address_space(3))) unsigned int*)(base + 8192 + c0 * 16), 16, 0, 0);
        __builtin_amdgcn_global_load_lds(
            (const __attribute__((address_space(1))) unsigned int*)(b1 + k0),
            (__attribute__((address_space(3))) unsigned int*)(base + 8192 + c1 * 16), 16, 0, 0);
    };

    f32x4 acc[4][4] = {};

    stage(0); stage(1); stage(2);
    asm volatile("s_waitcnt vmcnt(8)" ::: "memory");
    __builtin_amdgcn_s_barrier();

    for (int t = 0; t < NT; ++t) {
        const char* sA = (const char*)smem + (t & 3) * 16384;
        const char* sB = sA + 8192;

        bf16x8 af[4], bfr[4];
        #pragma unroll
        for (int mi = 0; mi < 4; ++mi)
            af[mi] = *(const bf16x8*)(sA + (wm + mi * 16 + rA) * 64 + swzB);
        #pragma unroll
        for (int ni = 0; ni < 4; ++ni)
            bfr[ni] = *(const bf16x8*)(sB + (wn + ni * 16 + rA) * 64 + swzB);

        if (t + 3 < NT) {
            stage(t + 3);
            asm volatile("s_waitcnt vmcnt(8)" ::: "memory");
        } else if (t + 2 < NT) {
            asm volatile("s_waitcnt vmcnt(4)" ::: "memory");
        } else {
            asm volatile("s_waitcnt vmcnt(0)" ::: "memory");
        }
        __builtin_amdgcn_s_barrier();

        __builtin_amdgcn_s_setprio(1);
        #pragma unroll
        for (int mi = 0; mi < 4; ++mi) {
            #pragma unroll
            for (int ni = 0; ni < 4; ++ni)
                acc[mi][ni] = __builtin_amdgcn_mfma_f32_16x16x32_bf16(af[mi], bfr[ni], acc[mi][ni], 0, 0, 0);
        }
        __builtin_amdgcn_s_setprio(0);
        __builtin_amdgcn_s_barrier();
    }

    #pragma unroll
    for (int mi = 0; mi < 4; ++mi) {
        #pragma unroll
        for (int ni = 0; ni < 4; ++ni) {
            const int col = bn0 + wn + ni * 16 + rA;
            if (col < N) {
                #pragma unroll
                for (int r = 0; r < 4; ++r) {
                    const int rowg = bm0 + wm + mi * 16 + ks * 4 + r;
                    float v = acc[mi][ni][r];
                    if (EPI == 0) {
                        ((bf16*)outv)[(size_t)rowg * ldo + col] =
                            (bf16)(fsigmoid(v) * ftanh(eaux[(size_t)rowg * ldo + col]));
                    } else {
                        ((float*)outv)[(size_t)rowg * ldo + col] = v;
                    }
                }
            }
        }
    }
}

// ---------------- gate with direct-f32 x staging (no xb conversion pass) ----------------
// gate = x(f32)@Wx^T + hprev@Wsh^T. Ring-3 x 24 KB slots (A 16KB f32 / 8KB bf16 | B 8KB)
// = 72 KB -> 2 blocks/CU. x phase: 4 f32 global_load_lds chunks/thread, frag read converts
// f32->bf16 (same cast as prep used -> bit-identical). hb phase: bf16 path, shifted rows.
// vmcnt: loads/tile L = 6 (x) or 4 (hb); at iter t wait vmcnt(L(t+2)) == "tile t+1 landed".
__device__ __forceinline__ void gate128f(
    char* smem, const float* __restrict__ xf, const bf16* __restrict__ Wxb,
    const bf16* __restrict__ hb, const bf16* __restrict__ Wshb,
    const float* __restrict__ cel, bf16* __restrict__ sentb,
    int bm0, int bn0, const bf16* __restrict__ zbuf)
{
    const int NT1 = EE >> 5;   // 32 x-tiles
    const int NT = NT1 + (HH >> 5);   // + 16 hb-tiles = 48

    const int tid = threadIdx.x;
    const int lane = tid & 63;
    const int wid = tid >> 6;
    const int wm = (wid >> 1) * 64;
    const int wn = (wid & 1) * 64;
    const int rA = lane & 15;
    const int ks = lane >> 4;
    const int swzB = (ks ^ ((rA >> 1) & 3)) * 16;

    // x staging: 1024 chunks (4/thread): row = c>>3 (0..127), slot = c&7 (8 x 16B per row)
    const float* xsrc[4];
    #pragma unroll
    for (int j = 0; j < 4; ++j) {
        const int c = tid + 256 * j;
        const int row = c >> 3, slot = c & 7;
        xsrc[j] = xf + (size_t)(bm0 + row) * EE + ((slot ^ ((row >> 1) & 7)) << 2);
    }
    // bf16 staging pattern (B both phases; A hb phase): 512 chunks (2/thread)
    const int cb0 = tid, cb1 = tid + 256;
    const int brow0 = cb0 >> 2, brow1 = cb1 >> 2;
    const int gb0 = ((cb0 & 3) ^ ((brow0 >> 1) & 3)) * 8;
    const int gb1 = ((cb1 & 3) ^ ((brow1 >> 1) & 3)) * 8;

    const bf16* B1r0 = Wxb + (size_t)(bn0 + brow0) * EE + gb0;
    const bf16* B1r1 = Wxb + (size_t)(bn0 + brow1) * EE + gb1;
    const bf16* B2r0 = Wshb + (size_t)(bn0 + brow0) * HH + gb0;
    const bf16* B2r1 = Wshb + (size_t)(bn0 + brow1) * HH + gb1;
    const bf16* A2r0 = (((bm0 + brow0) & 63) == 0) ? zbuf + gb0
                                                   : hb + (size_t)(bm0 + brow0 - 1) * HH + gb0;
    const bf16* A2r1 = (((bm0 + brow1) & 63) == 0) ? zbuf + gb1
                                                   : hb + (size_t)(bm0 + brow1 - 1) * HH + gb1;

    auto stage = [&](int t, int slot) {
        char* base = smem + slot * 24576;
        if (t < NT1) {
            const int k0 = t << 5;
            #pragma unroll
            for (int j = 0; j < 4; ++j)
                __builtin_amdgcn_global_load_lds(
                    (const __attribute__((address_space(1))) unsigned int*)(xsrc[j] + k0),
                    (__attribute__((address_space(3))) unsigned int*)(base + (tid + 256 * j) * 16), 16, 0, 0);
            __builtin_amdgcn_global_load_lds(
                (const __attribute__((address_space(1))) unsigned int*)(B1r0 + k0),
                (__attribute__((address_space(3))) unsigned int*)(base + 16384 + cb0 * 16), 16, 0, 0);
            __builtin_amdgcn_global_load_lds(
                (const __attribute__((address_space(1))) unsigned int*)(B1r1 + k0),
                (__attribute__((address_space(3))) unsigned int*)(base + 16384 + cb1 * 16), 16, 0, 0);
        } else {
            const int k0 = (t - NT1) << 5;
            __builtin_amdgcn_global_load_lds(
                (const __attribute__((address_space(1))) unsigned int*)(A2r0 + k0),
                (__attribute__((address_space(3))) unsigned int*)(base + cb0 * 16), 16, 0, 0);
            __builtin_amdgcn_global_load_lds(
                (const __attribute__((address_space(1))) unsigned int*)(A2r1 + k0),
                (__attribute__((address_space(3))) unsigned int*)(base + cb1 * 16), 16, 0, 0);
            __builtin_amdgcn_global_load_lds(
                (const __attribute__((address_space(1))) unsigned int*)(B2r0 + k0),
                (__attribute__((address_space(3))) unsigned int*)(base + 16384 + cb0 * 16), 16, 0, 0);
            __builtin_amdgcn_global_load_lds(
                (const __attribute__((address_space(1))) unsigned int*)(B2r1 + k0),
                (__attribute__((address_space(3))) unsigned int*)(base + 16384 + cb1 * 16), 16, 0, 0);
        }
    };

    f32x4 acc[4][4] = {};

    // prologue: tiles 0,1 into slots 0,1; vmcnt(6) = L(1) -> tile 0 landed
    stage(0, 0); stage(1, 1);
    asm volatile("s_waitcnt vmcnt(6)" ::: "memory");
    __builtin_amdgcn_s_barrier();

    int slR = 0, slS = 2;
    for (int t = 0; t < NT; ++t) {
        const char* base = smem + slR * 24576;
        const char* sB = base + 16384;

        bf16x8 af[4], bfr[4];
        if (t < NT1) {
            // f32 A frags: LDS[row][s] holds cols (s^m)*4, m=(row>>1)&7; want cols ks*8..+7
            #pragma unroll
            for (int mi = 0; mi < 4; ++mi) {
                const int row = wm + mi * 16 + rA;
                const int m = (row >> 1) & 7;
                f32x4 lo = *(const f32x4*)(base + row * 128 + (((2 * ks) ^ m) << 4));
                f32x4 hi = *(const f32x4*)(base + row * 128 + (((2 * ks + 1) ^ m) << 4));
                bf16x8 v = { (bf16)lo[0], (bf16)lo[1], (bf16)lo[2], (bf16)lo[3],
                             (bf16)hi[0], (bf16)hi[1], (bf16)hi[2], (bf16)hi[3] };
                af[mi] = v;
            }
        } else {
            #pragma unroll
            for (int mi = 0; mi < 4; ++mi)
                af[mi] = *(const bf16x8*)(base + (wm + mi * 16 + rA) * 64 + swzB);
        }
        #pragma unroll
        for (int ni = 0; ni < 4; ++ni)
            bfr[ni] = *(const bf16x8*)(sB + (wn + ni * 16 + rA) * 64 + swzB);

        if (t + 2 < NT) {
            stage(t + 2, slS);
            if (t + 2 < NT1) asm volatile("s_waitcnt vmcnt(6)" ::: "memory");
            else             asm volatile("s_waitcnt vmcnt(4)" ::: "memory");
        } else {
            asm volatile("s_waitcnt vmcnt(0)" ::: "memory");
        }
        __builtin_amdgcn_s_barrier();

        __builtin_amdgcn_s_setprio(1);
        #pragma unroll
        for (int mi = 0; mi < 4; ++mi) {
            #pragma unroll
            for (int ni = 0; ni < 4; ++ni)
                acc[mi][ni] = __builtin_amdgcn_mfma_f32_16x16x32_bf16(af[mi], bfr[ni], acc[mi][ni], 0, 0, 0);
        }
        __builtin_amdgcn_s_setprio(0);
        __builtin_amdgcn_s_barrier();

        slR = (slR == 2) ? 0 : slR + 1;
        slS = (slS == 2) ? 0 : slS + 1;
    }

    // epilogue: sentb = bf16(sigmoid(gate)*tanh(cells))
    #pragma unroll
    for (int mi = 0; mi < 4; ++mi) {
        #pragma unroll
        for (int ni = 0; ni < 4; ++ni) {
            const int col = bn0 + wn + ni * 16 + rA;
            #pragma unroll
            for (int r = 0; r < 4; ++r) {
                const int rowg = bm0 + wm + mi * 16 + ks * 4 + r;
                sentb[(size_t)rowg * HH + col] =
                    (bf16)(fsigmoid(acc[mi][ni][r]) * ftanh(cel[(size_t)rowg * HH + col]));
            }
        }
    }
}

// merged launch: gate (256) + cv (49) + cg (64) + Wm-convert filler (143) = 512 blocks.
// gate bids remapped so the 4 N-blocks sharing an M-panel land on the SAME XCD (L2 reuse
// of the f32 x reads): lin = (bid&7)*32 + (bid>>3); bm0 = (lin>>2)*128, bn0 = (lin&3)*128.
__global__ __launch_bounds__(256, 2)
void gate_mid128(const float* __restrict__ xf, const bf16* __restrict__ Wxb,
                 const bf16* __restrict__ Wshb,
                 const float* __restrict__ cel, bf16* __restrict__ sentb,
                 const bf16* __restrict__ Vb, const bf16* __restrict__ Wvb,
                 const bf16* __restrict__ hb, const bf16* __restrict__ Wgb,
                 float* __restrict__ cv, float* __restrict__ cg,
                 const float* __restrict__ Wm, bf16* __restrict__ Wmb,
                 const bf16* __restrict__ zbuf)
{
    __shared__ char smem[73728];   // 3 x 24 KB (gate); other branches use 64 KB of it
    const int bid = blockIdx.x;
    if (bid >= 369) {
        const long n4 = ((long)NV * HH) >> 2;
        for (long i4 = (long)(bid - 369) * 256 + threadIdx.x; i4 < n4; i4 += 143L * 256)
            cvt4nt(Wm + (i4 << 2), Wmb + (i4 << 2));
        return;
    }
    if (bid < 256) {
        const int lin = (bid & 7) * 32 + (bid >> 3);
        gate128f(smem, xf, Wxb, hb, Wshb, cel, sentb,
                 (lin >> 2) * 128, (lin & 3) * 128, zbuf);
    } else if (bid < 305) {
        gemm128_core<2, false>((bf16*)smem, Vb, Wvb, HH, nullptr, nullptr, 0, KA, nullptr,
                               (void*)cv, KA, (bid - 256) * 128, 0, nullptr);
    } else {
        gemm128_core<2, false>((bf16*)smem, hb, Wgb, HH, nullptr, nullptr, 0, KA, nullptr,
                               (void*)cg, KA, (bid - 305) * 128, 0, nullptr);
    }
}

// ---------------- cs64: cs_partial = sent@Ws^T (K=512 only; cg added in softz) ----------
__global__ __launch_bounds__(256, 2)
void cs64(const bf16* __restrict__ sentb, const bf16* __restrict__ Wsb,
          float* __restrict__ cs)
{
    __shared__ bf16 smem[4 * 4096];
    const int bm0 = blockIdx.x * 64;
    const int tid = threadIdx.x;
    const int lane = tid & 63;
    const int w = tid >> 6;
    const int rA = lane & 15;
    const int ks = lane >> 4;
    const int swzB = (ks ^ ((rA >> 1) & 3)) * 16;

    const int row = tid >> 2;
    const int gc = ((tid & 3) ^ ((row >> 1) & 3)) * 8;
    const int browc = (row < KA) ? row : KA - 1;
    const bf16* Ar = sentb + (size_t)(bm0 + row) * HH + gc;
    const bf16* Br = Wsb + (size_t)browc * HH + gc;

    auto stage = [&](int t) {
        char* base = (char*)smem + (t & 3) * 8192;
        const int k0 = t << 5;
        __builtin_amdgcn_global_load_lds(
            (const __attribute__((address_space(1))) unsigned int*)(Ar + k0),
            (__attribute__((address_space(3))) unsigned int*)(base + tid * 16), 16, 0, 0);
        __builtin_amdgcn_global_load_lds(
            (const __attribute__((address_space(1))) unsigned int*)(Br + k0),
            (__attribute__((address_space(3))) unsigned int*)(base + 4096 + tid * 16), 16, 0, 0);
    };

    f32x4 acc[4] = {};
    const int NT = HH / 32;

    stage(0); stage(1); stage(2);
    asm volatile("s_waitcnt vmcnt(4)" ::: "memory");
    __builtin_amdgcn_s_barrier();

    for (int t = 0; t < NT; ++t) {
        const char* sA = (const char*)smem + (t & 3) * 8192;
        const char* sB = sA + 4096;

        bf16x8 af[4];
        #pragma unroll
        for (int mi = 0; mi < 4; ++mi)
            af[mi] = *(const bf16x8*)(sA + (mi * 16 + rA) * 64 + swzB);
        bf16x8 bfr = *(const bf16x8*)(sB + (w * 16 + rA) * 64 + swzB);

        if (t + 3 < NT) {
            stage(t + 3);
            asm volatile("s_waitcnt vmcnt(4)" ::: "memory");
        } else if (t + 2 < NT) {
            asm volatile("s_waitcnt vmcnt(2)" ::: "memory");
        } else {
            asm volatile("s_waitcnt vmcnt(0)" ::: "memory");
        }
        __builtin_amdgcn_s_barrier();

        __builtin_amdgcn_s_setprio(1);
        #pragma unroll
        for (int mi = 0; mi < 4; ++mi)
            acc[mi] = __builtin_amdgcn_mfma_f32_16x16x32_bf16(af[mi], bfr, acc[mi], 0, 0, 0);
        __builtin_amdgcn_s_setprio(0);
        __builtin_amdgcn_s_barrier();
    }

    const int col = w * 16 + rA;
    if (col < KA) {
        #pragma unroll
        for (int mi = 0; mi < 4; ++mi) {
            #pragma unroll
            for (int r = 0; r < 4; ++r) {
                const int rowg = bm0 + mi * 16 + ks * 4 + r;
                cs[(size_t)rowg * KA + col] = acc[mi][r];
            }
        }
    }
}

// ---------------- z / alpha / beta (csv = cs_partial + cg) ----------------
__global__ __launch_bounds__(256)
void softz_kernel(const float* __restrict__ cv, const float* __restrict__ cg,
                  const float* __restrict__ cs, const float* __restrict__ wh,
                  float* __restrict__ alpha, float* __restrict__ beta)
{
    __shared__ float cvL[KA * KA];
    __shared__ float whL[64];
    __shared__ float cgL[4 * KA];

    const int tid = threadIdx.x;
    const int w = tid >> 6, lane = tid & 63;
    const int bt0 = blockIdx.x * 4;
    const int b = bt0 >> 6;
    const int bt = bt0 + w;

    const float* cvb = cv + (size_t)b * KA * KA;
    for (int i = tid; i < KA * KA; i += 256) cvL[i] = cvb[i];
    if (tid < KA) whL[tid] = wh[tid];
    if (lane < KA) cgL[w * KA + lane] = cg[(size_t)bt * KA + lane];
    float csv0 = (lane < KA) ? cs[(size_t)bt * KA + lane] : 0.f;
    __syncthreads();

    float z = -INFINITY;
    if (lane < KA) {
        const float* cvk = cvL + lane * KA;
        const float* cgr = cgL + w * KA;
        float acc = 0.f;
        #pragma unroll 7
        for (int n = 0; n < KA; ++n)
            acc += ftanh(cvk[n] + cgr[n]) * whL[n];
        z = acc;
    }
    const float csv = csv0 + ((lane < KA) ? cgL[w * KA + lane] : 0.f);
    float u = (lane < KA) ? ftanh(csv) * whL[lane] : 0.f;

    float m1 = z;
    #pragma unroll
    for (int o = 32; o; o >>= 1) m1 = fmaxf(m1, __shfl_xor(m1, o, 64));
    float e = (lane < KA) ? __expf(z - m1) : 0.f;
    float s1 = e, ze = u;
    #pragma unroll
    for (int o = 32; o; o >>= 1) { s1 += __shfl_xor(s1, o, 64); ze += __shfl_xor(ze, o, 64); }

    if (lane < KA) alpha[(size_t)bt * KA + lane] = e / s1;
    if (lane == 0) {
        float M2 = fmaxf(m1, ze);
        float denom = s1 * __expf(m1 - M2) + __expf(ze - M2);
        beta[bt] = __expf(ze - M2) / denom;
    }
}

// ---------------- c = alpha@V ; ch = beta*sent + (1-beta)*c + hiddens -> bf16 ----------------
__global__ __launch_bounds__(256)
void cch_kernel(const float* __restrict__ alpha, const float* __restrict__ beta,
                const bf16* __restrict__ Vb, const bf16* __restrict__ sentb,
                const float* __restrict__ hid, bf16* __restrict__ chb)
{
    __shared__ float aL[TT * KA];
    __shared__ float bL[TT];

    const int b = blockIdx.x >> 3;
    const int hc = blockIdx.x & 7;
    const int tid = threadIdx.x;
    const int w = tid >> 6, lane = tid & 63;
    const int h = hc * 64 + lane;

    const float* ab = alpha + (size_t)b * TT * KA;
    for (int i = tid; i < TT * KA; i += 256) aL[i] = ab[i];
    if (tid < TT) bL[tid] = beta[b * TT + tid];

    float vreg[KA];
    #pragma unroll
    for (int k = 0; k < KA; ++k) vreg[k] = (float)Vb[((size_t)b * KA + k) * HH + h];
    __syncthreads();

    #pragma unroll 1
    for (int tt = 0; tt < 16; ++tt) {
        const int t = w * 16 + tt;
        const int bt = b * TT + t;
        const float* ar = aL + t * KA;
        float c = 0.f;
        #pragma unroll
        for (int k = 0; k < KA; ++k) c += ar[k] * vreg[k];
        const float be = bL[t];
        const size_t idx = (size_t)bt * HH + h;
        float ch = be * (float)sentb[idx] + (1.f - be) * c
                 + __builtin_nontemporal_load(hid + idx);
        chb[idx] = (bf16)ch;
    }
}

// ---------------- 256x128 deep-pipelined GEMM for the output projection ----------------
__global__ __launch_bounds__(512, 4)
void gemm256x128_bias(const bf16* __restrict__ A, const bf16* __restrict__ B,
                      const float* __restrict__ bias, float* __restrict__ out)
{
    const int K = HH;
    const int N = NV;
    const int NT = K / 32;
    const int ntn = 79;

    __shared__ bf16 smem[3 * 12288];

    const int bid = blockIdx.x;
    const int wg = (bid & 7) * 316 + (bid >> 3);
    const int bm0 = (wg / ntn) * 256;
    const int bn0 = (wg % ntn) * 128;

    const int tid = threadIdx.x;
    const int lane = tid & 63;
    const int wid = tid >> 6;
    const int wr = (wid >> 1) * 64;
    const int wc = (wid & 1) * 64;
    const int rA = lane & 15;
    const int ks = lane >> 4;
    const int swz = (ks ^ ((rA >> 1) & 3)) * 16;

    const int arow0 = tid >> 2;
    const int arow1 = arow0 + 128;
    const int gcA0 = ((tid & 3) ^ ((arow0 >> 1) & 3)) * 8;
    const int gcA1 = ((tid & 3) ^ ((arow1 >> 1) & 3)) * 8;
    const int brow = tid >> 2;
    const int gcB  = ((tid & 3) ^ ((brow >> 1) & 3)) * 8;
    const int browc = (bn0 + brow < N) ? bn0 + brow : N - 1;

    const bf16* Ap0 = A + (size_t)(bm0 + arow0) * K + gcA0;
    const bf16* Ap1 = A + (size_t)(bm0 + arow1) * K + gcA1;
    const bf16* Bp  = B + (size_t)browc * K + gcB;

    auto stage = [&](int t, int slot) {
        char* base = (char*)smem + slot * 24576;
        const int k0 = t << 5;
        __builtin_amdgcn_global_load_lds(
            (const __attribute__((address_space(1))) unsigned int*)(Ap0 + k0),
            (__attribute__((address_space(3))) unsigned int*)(base + tid * 16), 16, 0, 0);
        __builtin_amdgcn_global_load_lds(
            (const __attribute__((address_space(1))) unsigned int*)(Ap1 + k0),
            (__attribute__((address_space(3))) unsigned int*)(base + (tid + 512) * 16), 16, 0, 0);
        __builtin_amdgcn_global_load_lds(
            (const __attribute__((address_space(1))) unsigned int*)(Bp + k0),
            (__attribute__((address_space(3))) unsigned int*)(base + 16384 + tid * 16), 16, 0, 0);
    };

    f32x4 acc[4][4] = {};

    stage(0, 0); stage(1, 1);
    asm volatile("s_waitcnt vmcnt(3)" ::: "memory");
    __builtin_amdgcn_s_barrier();

    int slR = 0, slS = 2;
    for (int t = 0; t < NT; ++t) {
        const char* sA = (const char*)smem + slR * 24576;
        const char* sB = sA + 16384;

        bf16x8 af[4], bfr[4];
        #pragma unroll
        for (int mi = 0; mi < 4; ++mi)
            af[mi] = *(const bf16x8*)(sA + (wr + mi * 16 + rA) * 64 + swz);
        #pragma unroll
        for (int ni = 0; ni < 4; ++ni)
            bfr[ni] = *(const bf16x8*)(sB + (wc + ni * 16 + rA) * 64 + swz);

        if (t + 2 < NT) {
            stage(t + 2, slS);
            asm volatile("s_waitcnt vmcnt(3)" ::: "memory");
        } else {
            asm volatile("s_waitcnt vmcnt(0)" ::: "memory");
        }
        __builtin_amdgcn_s_barrier();

        __builtin_amdgcn_s_setprio(1);
        #pragma unroll
        for (int mi = 0; mi < 4; ++mi) {
            #pragma unroll
            for (int ni = 0; ni < 4; ++ni)
                acc[mi][ni] = __builtin_amdgcn_mfma_f32_16x16x32_bf16(af[mi], bfr[ni], acc[mi][ni], 0, 0, 0);
        }
        __builtin_amdgcn_s_setprio(0);
        __builtin_amdgcn_s_barrier();

        slR = (slR == 2) ? 0 : slR + 1;
        slS = (slS == 2) ? 0 : slS + 1;
    }

    float bv[4];
    #pragma unroll
    for (int ni = 0; ni < 4; ++ni) {
        const int col = bn0 + wc + ni * 16 + rA;
        bv[ni] = (col < N) ? bias[col] : 0.f;
    }
    float* lt = (float*)smem + wid * 2048;
    #pragma unroll
    for (int half = 0; half < 2; ++half) {
        #pragma unroll
        for (int mi2 = 0; mi2 < 2; ++mi2) {
            const int mi = half * 2 + mi2;
            #pragma unroll
            for (int ni = 0; ni < 4; ++ni) {
                #pragma unroll
                for (int r = 0; r < 4; ++r) {
                    const int row = mi2 * 16 + ks * 4 + r;
                    const int col = ni * 16 + rA;
                    const int s = ((((row >> 2) & 3) ^ (row & 3)) << 4);
                    lt[row * 64 + (col ^ s)] = acc[mi][ni][r] + bv[ni];
                }
            }
        }
        #pragma unroll
        for (int i = 0; i < 8; ++i) {
            const int row = i * 4 + ks;
            const int c0 = rA * 4;
            const int s = ((((row >> 2) & 3) ^ (row & 3)) << 4);
            f32x4 v = *(const f32x4*)&lt[row * 64 + (c0 ^ s)];
            const int rowg = bm0 + wr + half * 32 + row;
            const int colg = bn0 + wc + c0;
            if (colg < N)
                __builtin_nontemporal_store(v, (f32x4*)&out[(size_t)rowg * N + colg]);
        }
    }
}

extern "C" void kernel_launch(void* const* d_in, const int* in_sizes, int n_in,
                              void* d_out, int out_size, void* d_ws, size_t ws_size,
                              hipStream_t stream)
{
    const float* x   = (const float*)d_in[0];
    const float* hid = (const float*)d_in[1];
    const float* cel = (const float*)d_in[2];
    const float* V   = (const float*)d_in[3];
    const float* Wv  = (const float*)d_in[4];
    const float* Wg  = (const float*)d_in[5];
    const float* Ws  = (const float*)d_in[6];
    const float* wh  = (const float*)d_in[7];
    const float* Wx  = (const float*)d_in[8];
    const float* Wsh = (const float*)d_in[9];
    const float* Wm  = (const float*)d_in[10];
    const float* bm  = (const float*)d_in[11];

    float* out_o   = (float*)d_out;
    float* alpha_o = out_o + (size_t)BTT * NV;
    float* beta_o  = alpha_o + (size_t)BTT * KA;

    char* p = (char*)d_ws;
    bf16* sentb = (bf16*)p; p += (size_t)BTT * HH * 2;
    bf16* chb   = (bf16*)p; p += (size_t)BTT * HH * 2;
    bf16* hb    = (bf16*)p; p += (size_t)BTT * HH * 2;
    bf16* Vb    = (bf16*)p; p += (size_t)BB * KA * HH * 2;
    bf16* Wxb   = (bf16*)p; p += (size_t)HH * EE * 2;
    bf16* Wshb  = (bf16*)p; p += (size_t)HH * HH * 2;
    bf16* Wmb   = (bf16*)p; p += (size_t)NV * HH * 2;
    bf16* Wvb   = (bf16*)p; p += (size_t)KA * HH * 2;
    bf16* Wgb   = (bf16*)p; p += (size_t)KA * HH * 2;
    bf16* Wsb   = (bf16*)p; p += (size_t)KA * HH * 2;
    bf16* zbuf  = (bf16*)p; p += 1024 * 2;
    float* cv   = (float*)p; p += (size_t)BB * KA * KA * 4;
    float* cg   = (float*)p; p += (size_t)BTT * KA * 4;
    float* cs   = (float*)p; p += (size_t)BTT * KA * 4;

    prep_kernel<<<2048, 256, 0, stream>>>(hid, V, Wv, Wg, Ws, Wx, Wsh,
                                          hb, Vb, Wvb, Wgb, Wsb, Wxb, Wshb, zbuf);

    // gate (256, direct-f32 x) + cv (49) + cg (64) + Wm-convert (143) = 512 blocks
    gate_mid128<<<512, 256, 0, stream>>>(x, Wxb, Wshb, cel, sentb,
                                         Vb, Wvb, hb, Wgb, cv, cg, Wm, Wmb, zbuf);

    // cs_partial = sent@Ws^T only (cg added in softz); 128 blocks, 64-row tiles
    cs64<<<128, 256, 0, stream>>>(sentb, Wsb, cs);

    softz_kernel<<<BTT / 4, 256, 0, stream>>>(cv, cg, cs, wh, alpha_o, beta_o);
    cch_kernel<<<BB * 8, 256, 0, stream>>>(alpha_o, beta_o, Vb, sentb, hid, chb);

    // output = ch@Wm^T + bm   (256x128 tiles, ring-3, 2 blocks/CU, transposed nt stores)
    gemm256x128_bias<<<32 * 79, 512, 0, stream>>>(chb, Wmb, bm, out_o);
}